// Round 1
// baseline (286.835 us; speedup 1.0000x reference)
//
#include <hip/hip_runtime.h>
#include <hip/hip_bf16.h>

#define VOCAB 32000
#define DIM 64
#define NB 16
#define SEQ 2048

typedef __attribute__((ext_vector_type(8))) short bf16x8;   // 8 bf16 in 4 VGPRs
typedef __attribute__((ext_vector_type(4))) float f32x4;

// round-to-nearest-even fp32 -> bf16 (inputs are finite normals; no NaN care)
__device__ __forceinline__ unsigned short f2bf(float f) {
    unsigned int u = __builtin_bit_cast(unsigned int, f);
    u = (u + 0x7fffu + ((u >> 16) & 1u)) >> 16;
    return (unsigned short)u;
}

// Gather weight rows per token and convert to bf16.
// One thread per 8 elements: 16*2048 tokens * 8 chunks = 262144 threads.
__global__ __launch_bounds__(256) void gather_cvt(
        const int* __restrict__ seq,
        const float* __restrict__ weight,
        unsigned short* __restrict__ embs) {
    int tid = blockIdx.x * 256 + threadIdx.x;
    int token = tid >> 3;
    int c = (tid & 7) * 8;
    int row = seq[token];
    const float* src = weight + (size_t)row * DIM + c;
    unsigned short o[8];
#pragma unroll
    for (int j = 0; j < 8; ++j) o[j] = f2bf(src[j]);
    *reinterpret_cast<bf16x8*>(embs + (size_t)token * DIM + c) =
        *reinterpret_cast<bf16x8*>(o);
}

// Per batch: C = E * E^T / 8, M=N=2048, K=64 (single k-tile, no LDS).
// Block = 128x128 tile of C, 4 waves, each wave 32 rows x 128 cols.
// Fragment layouts (verified learn_hip m89/m91/m120):
//   A[m=lane&15][k=(lane>>4)*8+j]  -> 16B contiguous per lane from E row
//   B[k=(lane>>4)*8+j][n=lane&15]  -> same pattern from E row (B = E^T)
//   C: col=lane&15, row=(lane>>4)*4+reg  (output symmetric, swap-safe)
__global__ __launch_bounds__(256) void synergy_gemm(
        const unsigned short* __restrict__ embs,
        float* __restrict__ out) {
    const int b    = blockIdx.z;
    const int n0   = blockIdx.x * 128;
    const int wave = threadIdx.x >> 6;
    const int lane = threadIdx.x & 63;
    const int m0   = blockIdx.y * 128 + wave * 32;
    const int r    = lane & 15;
    const int q    = lane >> 4;

    const unsigned short* eb = embs + (size_t)b * SEQ * DIM;

    bf16x8 a[2][2], bv[8][2];
#pragma unroll
    for (int mt = 0; mt < 2; ++mt) {
        const unsigned short* p = eb + (size_t)(m0 + mt * 16 + r) * DIM + q * 8;
        a[mt][0] = *reinterpret_cast<const bf16x8*>(p);
        a[mt][1] = *reinterpret_cast<const bf16x8*>(p + 32);
    }
#pragma unroll
    for (int nt = 0; nt < 8; ++nt) {
        const unsigned short* p = eb + (size_t)(n0 + nt * 16 + r) * DIM + q * 8;
        bv[nt][0] = *reinterpret_cast<const bf16x8*>(p);
        bv[nt][1] = *reinterpret_cast<const bf16x8*>(p + 32);
    }

    f32x4 acc[2][8];
#pragma unroll
    for (int mt = 0; mt < 2; ++mt)
#pragma unroll
        for (int nt = 0; nt < 8; ++nt) {
            f32x4 c = {0.f, 0.f, 0.f, 0.f};
            c = __builtin_amdgcn_mfma_f32_16x16x32_bf16(a[mt][0], bv[nt][0], c, 0, 0, 0);
            c = __builtin_amdgcn_mfma_f32_16x16x32_bf16(a[mt][1], bv[nt][1], c, 0, 0, 0);
            acc[mt][nt] = c;
        }

    // Epilogue: scale by 1/sqrt(64) and store. Each 16-lane group writes one
    // full aligned 64B line per (mt,reg,nt) -> no partial-line HBM waste.
#pragma unroll
    for (int mt = 0; mt < 2; ++mt)
#pragma unroll
        for (int reg = 0; reg < 4; ++reg) {
            int row = m0 + mt * 16 + q * 4 + reg;
            float* orow = out + (size_t)b * SEQ * SEQ + (size_t)row * SEQ + n0;
#pragma unroll
            for (int nt = 0; nt < 8; ++nt)
                orow[nt * 16 + r] = acc[mt][nt][reg] * 0.125f;
        }
}

extern "C" void kernel_launch(void* const* d_in, const int* in_sizes, int n_in,
                              void* d_out, int out_size, void* d_ws, size_t ws_size,
                              hipStream_t stream) {
    const int*   seq    = (const int*)d_in[0];     // [16,2048] int32
    const float* weight = (const float*)d_in[1];   // [32000,64] fp32
    float*       out    = (float*)d_out;           // [16,2048,2048] fp32
    unsigned short* embs = (unsigned short*)d_ws;  // [16,2048,64] bf16 = 4 MiB

    // gather+cvt: 262144 threads
    gather_cvt<<<dim3(262144 / 256), dim3(256), 0, stream>>>(seq, weight, embs);

    // GEMM: grid (n-tiles, m-tiles, batch)
    synergy_gemm<<<dim3(SEQ / 128, SEQ / 128, NB), dim3(256), 0, stream>>>(embs, out);
}